// Round 1
// baseline (832.049 us; speedup 1.0000x reference)
//
#include <hip/hip_runtime.h>
#include <cstdint>
#include <cmath>

#define B_ 2
#define S_ 2048
#define DIM_ 2048
#define H_ 16
#define HKV_ 4
#define HD_ 128
#define MQ_ (B_*S_)      // 4096 rows
#define NKV_ (HKV_*HD_)  // 512

typedef unsigned short u16;
typedef __bf16 bf16_t;
typedef bf16_t bf16x8 __attribute__((ext_vector_type(8)));
typedef u16 u16x8 __attribute__((ext_vector_type(8)));
typedef u16 u16x4 __attribute__((ext_vector_type(4)));
typedef float f32x4 __attribute__((ext_vector_type(4)));

__device__ __forceinline__ u16 f2bf(float f) {
  union { float f; uint32_t u; } v; v.f = f;
  return (u16)((v.u + 0x7FFFu + ((v.u >> 16) & 1u)) >> 16);
}

// ---------------- conversion kernels ----------------

// x (f32, row-major M x K) -> bf16 same layout, 4 elems/thread
__global__ void cvt_x_kernel(const float* __restrict__ in, u16* __restrict__ out, int n4) {
  int i = blockIdx.x * blockDim.x + threadIdx.x;
  if (i >= n4) return;
  float4 v = reinterpret_cast<const float4*>(in)[i];
  u16x4 o;
  o[0] = f2bf(v.x); o[1] = f2bf(v.y); o[2] = f2bf(v.z); o[3] = f2bf(v.w);
  reinterpret_cast<u16x4*>(out)[i] = o;
}

// w (f32, K x N row-major) -> wt (bf16, N x K row-major). Coalesced writes.
__global__ void wt_kernel(const float* __restrict__ w, u16* __restrict__ wt, int K, int N) {
  int idx = blockIdx.x * blockDim.x + threadIdx.x;
  if (idx >= N * K) return;
  int k = idx % K;
  int n = idx / K;
  wt[idx] = f2bf(w[(size_t)k * N + n]);
}

// RoPE: in f32 [b][s][nh][128] -> out bf16 same layout. One thread per (even,odd) pair.
__global__ void rope_kernel(const float* __restrict__ in, const float* __restrict__ cosp,
                            const float* __restrict__ sinp, u16* __restrict__ outp,
                            int nh, int npairs) {
  int i = blockIdx.x * blockDim.x + threadIdx.x;
  if (i >= npairs) return;
  int j = i & 63;            // pair index within head (HD/2 = 64)
  int rest = i >> 6;         // (b*S + s)*nh + head
  int s = (rest / nh) % S_;
  float2 t = reinterpret_cast<const float2*>(in)[i];   // elems 2i,2i+1
  float c = cosp[s * 64 + j], sn = sinp[s * 64 + j];
  u16 lo = f2bf(t.x * c - t.y * sn);
  u16 hi = f2bf(t.x * sn + t.y * c);
  reinterpret_cast<uint32_t*>(outp)[i] = (uint32_t)lo | ((uint32_t)hi << 16);
}

// V f32 [b][s][g][d] -> Vt bf16 [b][g][d][s]
__global__ void vt_kernel(const float* __restrict__ v, u16* __restrict__ vt, int total) {
  int idx = blockIdx.x * blockDim.x + threadIdx.x;
  if (idx >= total) return;
  int s = idx % S_;
  int d = (idx / S_) % HD_;
  int g = (idx / (S_ * HD_)) % HKV_;
  int b = idx / (S_ * HD_ * HKV_);
  vt[idx] = f2bf(v[((size_t)(b * S_ + s) * HKV_ + g) * HD_ + d]);
}

// ---------------- GEMM: C(f32, MxN) = A(bf16, MxK) * Bt(bf16, NxK)^T ----------------
// 64x64 tile, BK=32, 256 threads (4 waves, each 32x32 output)
__launch_bounds__(256)
__global__ void gemm_bf16_nt(const u16* __restrict__ A, const u16* __restrict__ Bt,
                             float* __restrict__ C, int M, int N, int K) {
  __shared__ u16 As[64][40];  // pad: 80B row stride (16B-aligned, 20-bank)
  __shared__ u16 Bs[64][40];
  const int t = threadIdx.x;
  const int wave = t >> 6, lane = t & 63;
  const int lr = lane & 15, lg = lane >> 4;
  const int m0 = blockIdx.y * 64, n0 = blockIdx.x * 64;
  const int wm = (wave >> 1) * 32, wn = (wave & 1) * 32;
  const int srow = t >> 2, scol = (t & 3) * 8;
  const u16* Ap = A + (size_t)(m0 + srow) * K + scol;
  const u16* Bp = Bt + (size_t)(n0 + srow) * K + scol;

  f32x4 acc[2][2] = {};
  for (int k0 = 0; k0 < K; k0 += 32) {
    __syncthreads();
    *reinterpret_cast<u16x8*>(&As[srow][scol]) = *reinterpret_cast<const u16x8*>(Ap + k0);
    *reinterpret_cast<u16x8*>(&Bs[srow][scol]) = *reinterpret_cast<const u16x8*>(Bp + k0);
    __syncthreads();
    bf16x8 af[2], bf[2];
#pragma unroll
    for (int i = 0; i < 2; i++) af[i] = *reinterpret_cast<const bf16x8*>(&As[wm + i * 16 + lr][lg * 8]);
#pragma unroll
    for (int j = 0; j < 2; j++) bf[j] = *reinterpret_cast<const bf16x8*>(&Bs[wn + j * 16 + lr][lg * 8]);
#pragma unroll
    for (int i = 0; i < 2; i++)
#pragma unroll
      for (int j = 0; j < 2; j++)
        acc[i][j] = __builtin_amdgcn_mfma_f32_16x16x32_bf16(af[i], bf[j], acc[i][j], 0, 0, 0);
  }
  // C/D layout (verified m89): col = lane&15, row = (lane>>4)*4 + reg
#pragma unroll
  for (int i = 0; i < 2; i++)
#pragma unroll
    for (int j = 0; j < 2; j++)
#pragma unroll
      for (int r = 0; r < 4; r++) {
        int row = m0 + wm + i * 16 + lg * 4 + r;
        int col = n0 + wn + j * 16 + lr;
        C[(size_t)row * N + col] = acc[i][j][r];
      }
}

// ---------------- flash attention ----------------
__device__ __forceinline__ float red_max16(float v) {
  v = fmaxf(v, __shfl_xor(v, 1));
  v = fmaxf(v, __shfl_xor(v, 2));
  v = fmaxf(v, __shfl_xor(v, 4));
  v = fmaxf(v, __shfl_xor(v, 8));
  return v;
}
__device__ __forceinline__ float red_sum16(float v) {
  v += __shfl_xor(v, 1); v += __shfl_xor(v, 2);
  v += __shfl_xor(v, 4); v += __shfl_xor(v, 8);
  return v;
}

// Qb bf16 [b][s][H][128] (post-RoPE), Kb bf16 [b][s][HKV][128] (post-RoPE),
// Vt bf16 [b][g][d][s], Ab bf16 [b][s][H][128] output.
// grid (S/64, H, B), 256 threads; wave w handles 16 q-rows.
__launch_bounds__(256)
__global__ void attn_kernel(const u16* __restrict__ Qb, const u16* __restrict__ Kb,
                            const u16* __restrict__ Vt, u16* __restrict__ Ab) {
  __shared__ u16 Plds[4][16][40];
  const int b = blockIdx.z, h = blockIdx.y;
  const int g = h >> 2;  // REP = 4
  const int wave = threadIdx.x >> 6, lane = threadIdx.x & 63;
  const int lr = lane & 15, lg = lane >> 4;
  const int qlo = blockIdx.x * 64 + wave * 16;
  const int qhi = qlo + 15;
  const float scale = 0.08838834764831845f;  // 1/sqrt(128)

  bf16x8 qf[4];
  const u16* qptr = Qb + ((size_t)((b * S_ + qlo + lr) * H_ + h)) * HD_ + lg * 8;
#pragma unroll
  for (int dk = 0; dk < 4; dk++)
    qf[dk] = *reinterpret_cast<const bf16x8*>(qptr + dk * 32);

  f32x4 oacc[8] = {};
  float mi[4], li[4];
#pragma unroll
  for (int r = 0; r < 4; r++) { mi[r] = -INFINITY; li[r] = 0.f; }

  for (int kc = 0; kc <= qhi; kc += 32) {
    f32x4 sa[2] = {};
#pragma unroll
    for (int nf = 0; nf < 2; nf++) {
      const u16* kptr = Kb + ((size_t)((b * S_ + kc + nf * 16 + lr) * HKV_ + g)) * HD_ + lg * 8;
#pragma unroll
      for (int dk = 0; dk < 4; dk++) {
        bf16x8 kf = *reinterpret_cast<const bf16x8*>(kptr + dk * 32);
        sa[nf] = __builtin_amdgcn_mfma_f32_16x16x32_bf16(qf[dk], kf, sa[nf], 0, 0, 0);
      }
    }
    // online softmax per row r (row = qlo + lg*4 + r, cols spread over 16 lanes)
#pragma unroll
    for (int r = 0; r < 4; r++) {
      const int qi = qlo + lg * 4 + r;
      float s0 = (kc + lr      <= qi) ? sa[0][r] * scale : -INFINITY;
      float s1 = (kc + 16 + lr <= qi) ? sa[1][r] * scale : -INFINITY;
      float mx = red_max16(fmaxf(s0, s1));
      float mnew = fmaxf(mi[r], mx);     // finite from chunk 0 onward
      float corr = __expf(mi[r] - mnew);
      float p0 = __expf(s0 - mnew);      // masked -> exp(-inf) = 0
      float p1 = __expf(s1 - mnew);
      float rs = red_sum16(p0 + p1);
      li[r] = li[r] * corr + rs;
      mi[r] = mnew;
#pragma unroll
      for (int df = 0; df < 8; df++) oacc[df][r] *= corr;
      Plds[wave][lg * 4 + r][lr]      = f2bf(p0);
      Plds[wave][lg * 4 + r][16 + lr] = f2bf(p1);
    }
    // P as A-operand (per-wave LDS, intra-wave -> no barrier needed)
    bf16x8 pf = *reinterpret_cast<const bf16x8*>(&Plds[wave][lr][lg * 8]);
#pragma unroll
    for (int df = 0; df < 8; df++) {
      const u16* vptr = Vt + ((size_t)((b * HKV_ + g) * HD_ + df * 16 + lr)) * S_ + kc + lg * 8;
      bf16x8 vf = *reinterpret_cast<const bf16x8*>(vptr);
      oacc[df] = __builtin_amdgcn_mfma_f32_16x16x32_bf16(pf, vf, oacc[df], 0, 0, 0);
    }
  }
  // epilogue: divide by li, write bf16 [b][s][H][128]
#pragma unroll
  for (int df = 0; df < 8; df++)
#pragma unroll
    for (int r = 0; r < 4; r++) {
      int row = qlo + lg * 4 + r;
      float v = oacc[df][r] / li[r];
      Ab[((size_t)((b * S_ + row) * H_ + h)) * HD_ + df * 16 + lr] = f2bf(v);
    }
}

// ---------------- launch ----------------
extern "C" void kernel_launch(void* const* d_in, const int* in_sizes, int n_in,
                              void* d_out, int out_size, void* d_ws, size_t ws_size,
                              hipStream_t stream) {
  const float* x    = (const float*)d_in[0];
  const float* cosp = (const float*)d_in[1];
  const float* sinp = (const float*)d_in[2];
  const float* wq   = (const float*)d_in[3];
  const float* wk   = (const float*)d_in[4];
  const float* wv   = (const float*)d_in[5];
  const float* wo   = (const float*)d_in[6];
  float* out = (float*)d_out;

  char* ws = (char*)d_ws;
  size_t off = 0;
  auto alloc = [&](size_t bytes) -> void* {
    void* p = ws + off;
    off += (bytes + 255) & ~(size_t)255;
    return p;
  };
  u16* xb    = (u16*)alloc((size_t)MQ_ * DIM_ * 2);
  u16* wqT   = (u16*)alloc((size_t)DIM_ * DIM_ * 2);
  u16* wkT   = (u16*)alloc((size_t)NKV_ * DIM_ * 2);
  u16* wvT   = (u16*)alloc((size_t)NKV_ * DIM_ * 2);
  u16* woT   = (u16*)alloc((size_t)DIM_ * DIM_ * 2);
  float* Qf  = (float*)alloc((size_t)MQ_ * DIM_ * 4);
  float* Kf  = (float*)alloc((size_t)MQ_ * NKV_ * 4);
  float* Vf  = (float*)alloc((size_t)MQ_ * NKV_ * 4);
  u16* Qb    = (u16*)alloc((size_t)MQ_ * DIM_ * 2);
  u16* Kb    = (u16*)alloc((size_t)MQ_ * NKV_ * 2);
  u16* Vt    = (u16*)alloc((size_t)MQ_ * NKV_ * 2);
  u16* Ab    = (u16*)alloc((size_t)MQ_ * DIM_ * 2);

  const int TB = 256;
  // conversions
  cvt_x_kernel<<<(MQ_ * DIM_ / 4 + TB - 1) / TB, TB, 0, stream>>>(x, xb, MQ_ * DIM_ / 4);
  wt_kernel<<<(DIM_ * DIM_ + TB - 1) / TB, TB, 0, stream>>>(wq, wqT, DIM_, DIM_);
  wt_kernel<<<(DIM_ * NKV_ + TB - 1) / TB, TB, 0, stream>>>(wk, wkT, DIM_, NKV_);
  wt_kernel<<<(DIM_ * NKV_ + TB - 1) / TB, TB, 0, stream>>>(wv, wvT, DIM_, NKV_);
  wt_kernel<<<(DIM_ * DIM_ + TB - 1) / TB, TB, 0, stream>>>(wo, woT, DIM_, DIM_);

  // projections
  gemm_bf16_nt<<<dim3(DIM_ / 64, MQ_ / 64), TB, 0, stream>>>(xb, wqT, Qf, MQ_, DIM_, DIM_);
  gemm_bf16_nt<<<dim3(NKV_ / 64, MQ_ / 64), TB, 0, stream>>>(xb, wkT, Kf, MQ_, NKV_, DIM_);
  gemm_bf16_nt<<<dim3(NKV_ / 64, MQ_ / 64), TB, 0, stream>>>(xb, wvT, Vf, MQ_, NKV_, DIM_);

  // RoPE + V transpose
  rope_kernel<<<(B_ * S_ * H_ * 64 + TB - 1) / TB, TB, 0, stream>>>(Qf, cosp, sinp, Qb, H_, B_ * S_ * H_ * 64);
  rope_kernel<<<(B_ * S_ * HKV_ * 64 + TB - 1) / TB, TB, 0, stream>>>(Kf, cosp, sinp, Kb, HKV_, B_ * S_ * HKV_ * 64);
  vt_kernel<<<(MQ_ * NKV_ + TB - 1) / TB, TB, 0, stream>>>(Vf, Vt, MQ_ * NKV_);

  // attention
  attn_kernel<<<dim3(S_ / 64, H_, B_), TB, 0, stream>>>(Qb, Kb, Vt, Ab);

  // output projection -> f32 d_out
  gemm_bf16_nt<<<dim3(DIM_ / 64, MQ_ / 64), TB, 0, stream>>>(Ab, woT, out, MQ_, DIM_, DIM_);
}

// Round 2
// 432.257 us; speedup vs baseline: 1.9249x; 1.9249x over previous
//
#include <hip/hip_runtime.h>
#include <cstdint>
#include <cmath>

#define B_ 2
#define S_ 2048
#define DIM_ 2048
#define H_ 16
#define HKV_ 4
#define HD_ 128
#define MQ_ (B_*S_)      // 4096 rows
#define NKV_ (HKV_*HD_)  // 512

typedef unsigned short u16;
typedef unsigned int u32;
typedef __bf16 bf16_t;
typedef bf16_t bf16x8 __attribute__((ext_vector_type(8)));
typedef bf16_t bf16x2 __attribute__((ext_vector_type(2)));
typedef u16 u16x8 __attribute__((ext_vector_type(8)));
typedef u16 u16x4 __attribute__((ext_vector_type(4)));
typedef float f32x4 __attribute__((ext_vector_type(4)));

__device__ __forceinline__ u16 f2bf(float f) {
  union { float f; uint32_t u; } v; v.f = f;
  return (u16)((v.u + 0x7FFFu + ((v.u >> 16) & 1u)) >> 16);
}

__device__ __forceinline__ u32 pkbf(float a, float b) {
  bf16x2 v; v[0] = (bf16_t)a; v[1] = (bf16_t)b;
  return __builtin_bit_cast(u32, v);
}

// ---------------- conversion kernels ----------------

// x (f32, row-major M x K) -> bf16 same layout, 4 elems/thread
__global__ void cvt_x_kernel(const float* __restrict__ in, u16* __restrict__ out, int n4) {
  int i = blockIdx.x * blockDim.x + threadIdx.x;
  if (i >= n4) return;
  float4 v = reinterpret_cast<const float4*>(in)[i];
  u16x4 o;
  o[0] = f2bf(v.x); o[1] = f2bf(v.y); o[2] = f2bf(v.z); o[3] = f2bf(v.w);
  reinterpret_cast<u16x4*>(out)[i] = o;
}

// Tiled transpose: w (f32, K x N) -> wt (bf16, N x K). Coalesced reads AND writes.
// grid (N/64, K/64), 256 threads.
__global__ void wtT_kernel(const float* __restrict__ w, u16* __restrict__ wt, int K, int N) {
  __shared__ u16 tile[64][66];
  const int n0 = blockIdx.x * 64, k0 = blockIdx.y * 64;
  const int tx = threadIdx.x & 63, ty = threadIdx.x >> 6;
#pragma unroll
  for (int i = 0; i < 16; i++) {
    int kr = ty + i * 4;
    tile[tx][kr] = f2bf(w[(size_t)(k0 + kr) * N + n0 + tx]);
  }
  __syncthreads();
#pragma unroll
  for (int i = 0; i < 16; i++) {
    int nr = ty + i * 4;
    wt[(size_t)(n0 + nr) * K + k0 + tx] = tile[nr][tx];
  }
}

// RoPE: in f32 [b][s][nh][128] -> out bf16 same layout. One thread per (even,odd) pair.
__global__ void rope_kernel(const float* __restrict__ in, const float* __restrict__ cosp,
                            const float* __restrict__ sinp, u16* __restrict__ outp,
                            int nh, int npairs) {
  int i = blockIdx.x * blockDim.x + threadIdx.x;
  if (i >= npairs) return;
  int j = i & 63;            // pair index within head (HD/2 = 64)
  int rest = i >> 6;         // (b*S + s)*nh + head
  int s = (rest / nh) % S_;
  float2 t = reinterpret_cast<const float2*>(in)[i];   // elems 2i,2i+1
  float c = cosp[s * 64 + j], sn = sinp[s * 64 + j];
  u16 lo = f2bf(t.x * c - t.y * sn);
  u16 hi = f2bf(t.x * sn + t.y * c);
  reinterpret_cast<uint32_t*>(outp)[i] = (uint32_t)lo | ((uint32_t)hi << 16);
}

// Tiled transpose V: f32 [b][s][g][d] -> bf16 Vt [b][g][d][s]
// grid (S/64, HD/64, B*HKV), 256 threads.
__global__ void vtT_kernel(const float* __restrict__ v, u16* __restrict__ vt) {
  __shared__ u16 tile[64][66];
  const int s0 = blockIdx.x * 64, d0 = blockIdx.y * 64;
  const int bg = blockIdx.z, b = bg >> 2, g = bg & 3;
  const int tx = threadIdx.x & 63, ty = threadIdx.x >> 6;
#pragma unroll
  for (int i = 0; i < 16; i++) {
    int sr = ty + i * 4;
    tile[tx][sr] = f2bf(v[((size_t)(b * S_ + s0 + sr) * HKV_ + g) * HD_ + d0 + tx]);
  }
  __syncthreads();
#pragma unroll
  for (int i = 0; i < 16; i++) {
    int dr = ty + i * 4;
    vt[((size_t)bg * HD_ + d0 + dr) * S_ + s0 + tx] = tile[dr][tx];
  }
}

// ---------------- GEMM: C(f32, MxN) = A(bf16, MxK) * Bt(bf16, NxK)^T ----------------
// 64x64 tile, BK=32, 256 threads (4 waves, each 32x32 output)
__launch_bounds__(256)
__global__ void gemm_bf16_nt(const u16* __restrict__ A, const u16* __restrict__ Bt,
                             float* __restrict__ C, int M, int N, int K) {
  __shared__ u16 As[64][40];
  __shared__ u16 Bs[64][40];
  const int t = threadIdx.x;
  const int wave = t >> 6, lane = t & 63;
  const int lr = lane & 15, lg = lane >> 4;
  const int m0 = blockIdx.y * 64, n0 = blockIdx.x * 64;
  const int wm = (wave >> 1) * 32, wn = (wave & 1) * 32;
  const int srow = t >> 2, scol = (t & 3) * 8;
  const u16* Ap = A + (size_t)(m0 + srow) * K + scol;
  const u16* Bp = Bt + (size_t)(n0 + srow) * K + scol;

  f32x4 acc[2][2] = {};
  for (int k0 = 0; k0 < K; k0 += 32) {
    __syncthreads();
    *reinterpret_cast<u16x8*>(&As[srow][scol]) = *reinterpret_cast<const u16x8*>(Ap + k0);
    *reinterpret_cast<u16x8*>(&Bs[srow][scol]) = *reinterpret_cast<const u16x8*>(Bp + k0);
    __syncthreads();
    bf16x8 af[2], bf[2];
#pragma unroll
    for (int i = 0; i < 2; i++) af[i] = *reinterpret_cast<const bf16x8*>(&As[wm + i * 16 + lr][lg * 8]);
#pragma unroll
    for (int j = 0; j < 2; j++) bf[j] = *reinterpret_cast<const bf16x8*>(&Bs[wn + j * 16 + lr][lg * 8]);
#pragma unroll
    for (int i = 0; i < 2; i++)
#pragma unroll
      for (int j = 0; j < 2; j++)
        acc[i][j] = __builtin_amdgcn_mfma_f32_16x16x32_bf16(af[i], bf[j], acc[i][j], 0, 0, 0);
  }
#pragma unroll
  for (int i = 0; i < 2; i++)
#pragma unroll
    for (int j = 0; j < 2; j++)
#pragma unroll
      for (int r = 0; r < 4; r++) {
        int row = m0 + wm + i * 16 + lg * 4 + r;
        int col = n0 + wn + j * 16 + lr;
        C[(size_t)row * N + col] = acc[i][j][r];
      }
}

// ---------------- flash attention v2 ----------------
// 4 waves, 64 q-rows/block (16/wave), 64-key chunks.
// K,V double-buffered in LDS via global_load_lds (XOR-swizzled source),
// swapped QK^T (mfma(K,Q)) so softmax is lane-local over q=lr.
__launch_bounds__(256)
__global__ void attn_kernel(const u16* __restrict__ Qb, const u16* __restrict__ Kb,
                            const u16* __restrict__ Vt, u16* __restrict__ Ab) {
  __shared__ u16 Ks[2][64 * 128];   // [key][d], swizzled
  __shared__ u16 Vs[2][64 * 128];   // [d][key] (128 rows x 64 cols), swizzled
  __shared__ u16 Pl[4][16 * 64];    // per-wave P [q][key], swizzled

  const int b = blockIdx.z, h = blockIdx.y;
  const int g = h >> 2;                               // REP = 4
  const int qt = (int)gridDim.x - 1 - (int)blockIdx.x; // heavy tiles first
  const int tid = threadIdx.x;
  const int w = tid >> 6, lane = tid & 63;
  const int lr = lane & 15, lg = lane >> 4;
  const int qlo = qt * 64 + w * 16;
  const int qi = qlo + lr;                            // this lane's q index
  const u32 sw = (u32)((lr & 7) << 4);                // XOR swizzle for rows where row&7 == lr&7
  const float k1 = (float)(0.08838834764831845 * 1.4426950408889634); // scale*log2(e)

  // Q fragments (B-operand): Q[qlo+lr][lg*8 + dk*32]
  bf16x8 qf[4];
  const u16* qptr = Qb + ((size_t)((b * S_ + qlo + lr) * H_ + h)) * HD_ + lg * 8;
#pragma unroll
  for (int dk = 0; dk < 4; dk++)
    qf[dk] = *reinterpret_cast<const bf16x8*>(qptr + dk * 32);

  f32x4 oacc[8] = {};
  float m = -INFINITY, li = 0.f;

  const char* kgb = (const char*)Kb + ((size_t)b * S_ * HKV_ * HD_ + g * HD_) * 2;
  const char* vgb = (const char*)Vt + ((size_t)(b * HKV_ + g) * HD_) * (size_t)S_ * 2;
  const int nc = qt + 1;

  auto stage = [&](int buf, int kc) {
#pragma unroll
    for (int j = 0; j < 4; j++) {            // K: 16KB, this wave's 4x1KB slices
      int L = (w * 4 + j) * 1024 + lane * 16;
      int row = L >> 8;
      int slot = (L >> 4) & 15;
      int col = (slot ^ (row & 7)) << 4;
      const char* src = kgb + (size_t)(kc + row) * (HKV_ * HD_ * 2) + col;
      __builtin_amdgcn_global_load_lds(
          (const __attribute__((address_space(1))) unsigned int*)src,
          (__attribute__((address_space(3))) unsigned int*)((char*)&Ks[buf][0] + (w * 4 + j) * 1024),
          16, 0, 0);
    }
#pragma unroll
    for (int j = 0; j < 4; j++) {            // V: 16KB
      int L = (w * 4 + j) * 1024 + lane * 16;
      int d = L >> 7;
      int slot = (L >> 4) & 7;
      int col = (slot ^ (d & 7)) << 4;
      const char* src = vgb + ((size_t)d * S_ + kc) * 2 + col;
      __builtin_amdgcn_global_load_lds(
          (const __attribute__((address_space(1))) unsigned int*)src,
          (__attribute__((address_space(3))) unsigned int*)((char*)&Vs[buf][0] + (w * 4 + j) * 1024),
          16, 0, 0);
    }
  };

  stage(0, 0);
  __syncthreads();   // drains vmcnt(0) before barrier

  int buf = 0;
  char* prow = (char*)&Pl[w][0] + lr * 128;

  for (int c = 0; c < nc; ++c) {
    const int kc = c * 64;
    if (c + 1 < nc) stage(buf ^ 1, kc + 64);

    const char* kb_l = (const char*)&Ks[buf][0];
    const char* vb_l = (const char*)&Vs[buf][0];

    // QK^T swapped: sa[nf] = K-block * Q -> D[key=lg*4+r (within nf*16)][q=lr]
    f32x4 sa[4] = {};
#pragma unroll
    for (int nf = 0; nf < 4; nf++) {
      const int rb = (nf * 16 + lr) * 256;
#pragma unroll
      for (int dk = 0; dk < 4; dk++) {
        bf16x8 kf = *reinterpret_cast<const bf16x8*>(kb_l + rb + (((u32)(dk * 64 + lg * 16)) ^ sw));
        sa[nf] = __builtin_amdgcn_mfma_f32_16x16x32_bf16(kf, qf[dk], sa[nf], 0, 0, 0);
      }
    }

    // scale (exp2 domain) + causal mask (only diagonal chunks)
    float t[16];
    const bool full = (kc + 63 <= qlo);
#pragma unroll
    for (int nf = 0; nf < 4; nf++)
#pragma unroll
      for (int r = 0; r < 4; r++) {
        float v = sa[nf][r] * k1;
        if (!full) v = (kc + nf * 16 + lg * 4 + r <= qi) ? v : -INFINITY;
        t[nf * 4 + r] = v;
      }

    // max over 64 keys for q=lr: 15 in-lane fmax + 2 shuffles
    float tm = t[0];
#pragma unroll
    for (int i = 1; i < 16; i++) tm = fmaxf(tm, t[i]);
    tm = fmaxf(tm, __shfl_xor(tm, 16));
    tm = fmaxf(tm, __shfl_xor(tm, 32));

    // defer-max rescale (T13, THR=8 in log2 domain)
    if (!__all(tm <= m + 8.f)) {
      float mnew = fmaxf(m, tm);
      float corr = __builtin_amdgcn_exp2f(m - mnew);
      li *= corr;
#pragma unroll
      for (int r = 0; r < 4; r++) {
        float cc = __shfl(corr, (lane & 48) + lg * 4 + r);  // fetch corr for oacc row q=lg*4+r
#pragma unroll
        for (int df = 0; df < 8; df++) oacc[df][r] *= cc;
      }
      m = mnew;
    }

    // P = exp2(t - m), row-sum, pack to bf16 and write swizzled P rows
    float ps = 0.f;
#pragma unroll
    for (int nf = 0; nf < 4; nf++) {
      float p0 = __builtin_amdgcn_exp2f(t[nf * 4 + 0] - m);
      float p1 = __builtin_amdgcn_exp2f(t[nf * 4 + 1] - m);
      float p2 = __builtin_amdgcn_exp2f(t[nf * 4 + 2] - m);
      float p3 = __builtin_amdgcn_exp2f(t[nf * 4 + 3] - m);
      ps += (p0 + p1) + (p2 + p3);
      *(u32*)(prow + (((u32)(nf * 32 + lg * 8)) ^ sw))     = pkbf(p0, p1);
      *(u32*)(prow + (((u32)(nf * 32 + lg * 8 + 4)) ^ sw)) = pkbf(p2, p3);
    }
    ps += __shfl_xor(ps, 16);
    ps += __shfl_xor(ps, 32);
    li += ps;

    asm volatile("" ::: "memory");  // order P stores before P loads (mixed-type LDS access)

    // PV: oacc[df] += P[q][k] * V^T[d][k]
#pragma unroll
    for (int kh = 0; kh < 2; kh++) {
      bf16x8 pf = *reinterpret_cast<const bf16x8*>(prow + (((u32)(kh * 64 + lg * 16)) ^ sw));
#pragma unroll
      for (int df = 0; df < 8; df++) {
        const int row = df * 16 + lr;
        bf16x8 vf = *reinterpret_cast<const bf16x8*>(vb_l + row * 128 + (((u32)(kh * 64 + lg * 16)) ^ sw));
        oacc[df] = __builtin_amdgcn_mfma_f32_16x16x32_bf16(pf, vf, oacc[df], 0, 0, 0);
      }
    }

    __syncthreads();  // waits vmcnt(0): next chunk staged; all waves done with buf
    buf ^= 1;
  }

  // epilogue: normalize by li (fetched into oacc row domain), write bf16
#pragma unroll
  for (int r = 0; r < 4; r++) {
    float lsum = __shfl(li, (lane & 48) + lg * 4 + r);
    float inv = 1.f / lsum;
    const int qrow = qlo + lg * 4 + r;
    u16* orow = Ab + ((size_t)((b * S_ + qrow) * H_ + h)) * HD_ + lr;
#pragma unroll
    for (int df = 0; df < 8; df++)
      orow[df * 16] = f2bf(oacc[df][r] * inv);
  }
}

// ---------------- launch ----------------
extern "C" void kernel_launch(void* const* d_in, const int* in_sizes, int n_in,
                              void* d_out, int out_size, void* d_ws, size_t ws_size,
                              hipStream_t stream) {
  const float* x    = (const float*)d_in[0];
  const float* cosp = (const float*)d_in[1];
  const float* sinp = (const float*)d_in[2];
  const float* wq   = (const float*)d_in[3];
  const float* wk   = (const float*)d_in[4];
  const float* wv   = (const float*)d_in[5];
  const float* wo   = (const float*)d_in[6];
  float* out = (float*)d_out;

  char* ws = (char*)d_ws;
  size_t off = 0;
  auto alloc = [&](size_t bytes) -> void* {
    void* p = ws + off;
    off += (bytes + 255) & ~(size_t)255;
    return p;
  };
  u16* xb    = (u16*)alloc((size_t)MQ_ * DIM_ * 2);
  u16* wqT   = (u16*)alloc((size_t)DIM_ * DIM_ * 2);
  u16* wkT   = (u16*)alloc((size_t)NKV_ * DIM_ * 2);
  u16* wvT   = (u16*)alloc((size_t)NKV_ * DIM_ * 2);
  u16* woT   = (u16*)alloc((size_t)DIM_ * DIM_ * 2);
  float* Qf  = (float*)alloc((size_t)MQ_ * DIM_ * 4);
  float* Kf  = (float*)alloc((size_t)MQ_ * NKV_ * 4);
  float* Vf  = (float*)alloc((size_t)MQ_ * NKV_ * 4);
  u16* Qb    = (u16*)alloc((size_t)MQ_ * DIM_ * 2);
  u16* Kb    = (u16*)alloc((size_t)MQ_ * NKV_ * 2);
  u16* Vt    = (u16*)alloc((size_t)MQ_ * NKV_ * 2);
  u16* Ab    = (u16*)alloc((size_t)MQ_ * DIM_ * 2);

  const int TB = 256;
  // conversions (tiled transposes: coalesced reads + writes)
  cvt_x_kernel<<<(MQ_ * DIM_ / 4 + TB - 1) / TB, TB, 0, stream>>>(x, xb, MQ_ * DIM_ / 4);
  wtT_kernel<<<dim3(DIM_ / 64, DIM_ / 64), TB, 0, stream>>>(wq, wqT, DIM_, DIM_);
  wtT_kernel<<<dim3(NKV_ / 64, DIM_ / 64), TB, 0, stream>>>(wk, wkT, DIM_, NKV_);
  wtT_kernel<<<dim3(NKV_ / 64, DIM_ / 64), TB, 0, stream>>>(wv, wvT, DIM_, NKV_);
  wtT_kernel<<<dim3(DIM_ / 64, DIM_ / 64), TB, 0, stream>>>(wo, woT, DIM_, DIM_);

  // projections
  gemm_bf16_nt<<<dim3(DIM_ / 64, MQ_ / 64), TB, 0, stream>>>(xb, wqT, Qf, MQ_, DIM_, DIM_);
  gemm_bf16_nt<<<dim3(NKV_ / 64, MQ_ / 64), TB, 0, stream>>>(xb, wkT, Kf, MQ_, NKV_, DIM_);
  gemm_bf16_nt<<<dim3(NKV_ / 64, MQ_ / 64), TB, 0, stream>>>(xb, wvT, Vf, MQ_, NKV_, DIM_);

  // RoPE + V transpose
  rope_kernel<<<(B_ * S_ * H_ * 64 + TB - 1) / TB, TB, 0, stream>>>(Qf, cosp, sinp, Qb, H_, B_ * S_ * H_ * 64);
  rope_kernel<<<(B_ * S_ * HKV_ * 64 + TB - 1) / TB, TB, 0, stream>>>(Kf, cosp, sinp, Kb, HKV_, B_ * S_ * HKV_ * 64);
  vtT_kernel<<<dim3(S_ / 64, HD_ / 64, B_ * HKV_), TB, 0, stream>>>(Vf, Vt);

  // attention
  attn_kernel<<<dim3(S_ / 64, H_, B_), TB, 0, stream>>>(Qb, Kb, Vt, Ab);

  // output projection -> f32 d_out
  gemm_bf16_nt<<<dim3(DIM_ / 64, MQ_ / 64), TB, 0, stream>>>(Ab, woT, out, MQ_, DIM_, DIM_);
}

// Round 3
// 297.757 us; speedup vs baseline: 2.7944x; 1.4517x over previous
//
#include <hip/hip_runtime.h>
#include <cstdint>
#include <cmath>

#define B_ 2
#define S_ 2048
#define DIM_ 2048
#define H_ 16
#define HKV_ 4
#define HD_ 128
#define MQ_ (B_*S_)      // 4096 rows
#define NKV_ (HKV_*HD_)  // 512
#define NQKV_ 3072       // fused QKV output width
#define KOFF_ 2048       // col offset of K block in fused buffer
#define VOFF_ 2560       // col offset of V block

typedef unsigned short u16;
typedef unsigned int u32;
typedef __bf16 bf16_t;
typedef bf16_t bf16x8 __attribute__((ext_vector_type(8)));
typedef bf16_t bf16x2 __attribute__((ext_vector_type(2)));
typedef u16 u16x8 __attribute__((ext_vector_type(8)));
typedef u16 u16x4 __attribute__((ext_vector_type(4)));
typedef float f32x4 __attribute__((ext_vector_type(4)));

__device__ __forceinline__ u16 f2bf(float f) {
  union { float f; uint32_t u; } v; v.f = f;
  return (u16)((v.u + 0x7FFFu + ((v.u >> 16) & 1u)) >> 16);
}

__device__ __forceinline__ u32 pkbf(float a, float b) {
  bf16x2 v; v[0] = (bf16_t)a; v[1] = (bf16_t)b;
  return __builtin_bit_cast(u32, v);
}

__device__ __forceinline__ float bf2f(u16 u) {
  union { u32 u; float f; } v; v.u = ((u32)u) << 16;
  return v.f;
}

// ---------------- conversion kernels ----------------

// x (f32, row-major M x K) -> bf16 same layout, 4 elems/thread
__global__ void cvt_x_kernel(const float* __restrict__ in, u16* __restrict__ out, int n4) {
  int i = blockIdx.x * blockDim.x + threadIdx.x;
  if (i >= n4) return;
  float4 v = reinterpret_cast<const float4*>(in)[i];
  u16x4 o;
  o[0] = f2bf(v.x); o[1] = f2bf(v.y); o[2] = f2bf(v.z); o[3] = f2bf(v.w);
  reinterpret_cast<u16x4*>(out)[i] = o;
}

// Tiled transpose: w (f32, K x N) -> wt (bf16, N x K). Coalesced reads AND writes.
// grid (N/64, K/64), 256 threads.
__global__ void wtT_kernel(const float* __restrict__ w, u16* __restrict__ wt, int K, int N) {
  __shared__ u16 tile[64][66];
  const int n0 = blockIdx.x * 64, k0 = blockIdx.y * 64;
  const int tx = threadIdx.x & 63, ty = threadIdx.x >> 6;
#pragma unroll
  for (int i = 0; i < 16; i++) {
    int kr = ty + i * 4;
    tile[tx][kr] = f2bf(w[(size_t)(k0 + kr) * N + n0 + tx]);
  }
  __syncthreads();
#pragma unroll
  for (int i = 0; i < 16; i++) {
    int nr = ty + i * 4;
    wt[(size_t)(n0 + nr) * K + k0 + tx] = tile[nr][tx];
  }
}

// RoPE in-place on bf16 fused-QKV buffer. buf points at the Q (or K) block origin;
// tokens stride NQKV_ elems, nh heads x 128 per token region. One thread per pair.
__global__ void rope_bf_kernel(u16* __restrict__ buf, const float* __restrict__ cosp,
                               const float* __restrict__ sinp, int nh, int npairs) {
  int i = blockIdx.x * blockDim.x + threadIdx.x;
  if (i >= npairs) return;
  int j = i & 63;                 // pair index within head
  int head = (i >> 6) % nh;
  int token = i / (nh * 64);
  int s = token % S_;
  u16* p = buf + (size_t)token * NQKV_ + head * HD_ + j * 2;
  u32 v = *reinterpret_cast<u32*>(p);
  float t0 = bf2f((u16)(v & 0xFFFF));
  float t1 = bf2f((u16)(v >> 16));
  float c = cosp[s * 64 + j], sn = sinp[s * 64 + j];
  u16 lo = f2bf(t0 * c - t1 * sn);
  u16 hi = f2bf(t0 * sn + t1 * c);
  *reinterpret_cast<u32*>(p) = (u32)lo | ((u32)hi << 16);
}

// Tiled transpose V: bf16 fused buf col VOFF_.. -> bf16 Vt [b][g][d][s]
// grid (S/64, HD/64, B*HKV), 256 threads.
__global__ void vtT_kernel(const u16* __restrict__ qkv, u16* __restrict__ vt) {
  __shared__ u16 tile[64][66];
  const int s0 = blockIdx.x * 64, d0 = blockIdx.y * 64;
  const int bg = blockIdx.z, b = bg >> 2, g = bg & 3;
  const int tx = threadIdx.x & 63, ty = threadIdx.x >> 6;
#pragma unroll
  for (int i = 0; i < 16; i++) {
    int sr = ty + i * 4;
    tile[tx][sr] = qkv[(size_t)(b * S_ + s0 + sr) * NQKV_ + VOFF_ + g * HD_ + d0 + tx];
  }
  __syncthreads();
#pragma unroll
  for (int i = 0; i < 16; i++) {
    int dr = ty + i * 4;
    vt[((size_t)bg * HD_ + d0 + dr) * S_ + s0 + tx] = tile[dr][tx];
  }
}

// ---------------- m97-structure GEMM ----------------
// C(MxN) = A(bf16 MxK) * Bt(bf16 NxK)^T. 128x128 tile, BK=32, 256 threads.
// 4 waves (2x2), each computes 64x64 (4x4 frags of 16x16x32).
// Staging: global_load_lds width=16, linear LDS [128][32].
template <typename OutT>
__launch_bounds__(256)
__global__ void gemm128(const u16* __restrict__ A, const u16* __restrict__ Bt,
                        OutT* __restrict__ C, int M, int N, int K) {
  __shared__ u16 As[128 * 32];
  __shared__ u16 Bs[128 * 32];
  const int t = threadIdx.x;
  const int w = t >> 6, lane = t & 63;
  const int lr = lane & 15, lg = lane >> 4;
  const int m0 = blockIdx.y * 128, n0 = blockIdx.x * 128;
  const int wm = (w >> 1) * 64, wn = (w & 1) * 64;
  const int srow = lane >> 2, scol = (lane & 3) * 8;   // 16 rows x 32 cols per 64-lane slice

  f32x4 acc[4][4] = {};

  for (int k0 = 0; k0 < K; k0 += 32) {
    __syncthreads();   // all waves done reading As/Bs of prev step
#pragma unroll
    for (int j = 0; j < 2; j++) {
      const u16* asrc = A + (size_t)(m0 + w * 32 + j * 16 + srow) * K + k0 + scol;
      __builtin_amdgcn_global_load_lds(
          (const __attribute__((address_space(1))) unsigned int*)asrc,
          (__attribute__((address_space(3))) unsigned int*)((char*)As + w * 2048 + j * 1024 + lane * 16),
          16, 0, 0);
      const u16* bsrc = Bt + (size_t)(n0 + w * 32 + j * 16 + srow) * K + k0 + scol;
      __builtin_amdgcn_global_load_lds(
          (const __attribute__((address_space(1))) unsigned int*)bsrc,
          (__attribute__((address_space(3))) unsigned int*)((char*)Bs + w * 2048 + j * 1024 + lane * 16),
          16, 0, 0);
    }
    __syncthreads();   // vmcnt(0) drained before barrier -> tiles ready

    bf16x8 af[4], bf[4];
#pragma unroll
    for (int i = 0; i < 4; i++)
      af[i] = *reinterpret_cast<const bf16x8*>((char*)As + (wm + i * 16 + lr) * 64 + lg * 16);
#pragma unroll
    for (int j = 0; j < 4; j++)
      bf[j] = *reinterpret_cast<const bf16x8*>((char*)Bs + (wn + j * 16 + lr) * 64 + lg * 16);
#pragma unroll
    for (int i = 0; i < 4; i++)
#pragma unroll
      for (int j = 0; j < 4; j++)
        acc[i][j] = __builtin_amdgcn_mfma_f32_16x16x32_bf16(af[i], bf[j], acc[i][j], 0, 0, 0);
  }

  // epilogue: C/D layout col=lane&15, row=(lane>>4)*4+reg
#pragma unroll
  for (int i = 0; i < 4; i++)
#pragma unroll
    for (int j = 0; j < 4; j++)
#pragma unroll
      for (int r = 0; r < 4; r++) {
        int row = m0 + wm + i * 16 + lg * 4 + r;
        int col = n0 + wn + j * 16 + lr;
        if constexpr (__is_same(OutT, float))
          C[(size_t)row * N + col] = acc[i][j][r];
        else
          C[(size_t)row * N + col] = f2bf(acc[i][j][r]);
      }
}

// ---------------- flash attention (round-2 structure, fused-QKV strides) ----------------
__launch_bounds__(256)
__global__ void attn_kernel(const u16* __restrict__ Qc, const u16* __restrict__ Kc,
                            const u16* __restrict__ Vt, u16* __restrict__ Ab) {
  __shared__ u16 Ks[2][64 * 128];   // [key][d], swizzled
  __shared__ u16 Vs[2][64 * 128];   // [d][key], swizzled
  __shared__ u16 Pl[4][16 * 64];    // per-wave P [q][key], swizzled

  const int b = blockIdx.z, h = blockIdx.y;
  const int g = h >> 2;                               // REP = 4
  const int qt = (int)gridDim.x - 1 - (int)blockIdx.x; // heavy tiles first
  const int tid = threadIdx.x;
  const int w = tid >> 6, lane = tid & 63;
  const int lr = lane & 15, lg = lane >> 4;
  const int qlo = qt * 64 + w * 16;
  const int qi = qlo + lr;
  const u32 sw = (u32)((lr & 7) << 4);
  const float k1 = (float)(0.08838834764831845 * 1.4426950408889634); // scale*log2(e)

  // Q fragments (B-operand): Q[qlo+lr][lg*8 + dk*32], token stride NQKV_
  bf16x8 qf[4];
  const u16* qptr = Qc + (size_t)(b * S_ + qlo + lr) * NQKV_ + h * HD_ + lg * 8;
#pragma unroll
  for (int dk = 0; dk < 4; dk++)
    qf[dk] = *reinterpret_cast<const bf16x8*>(qptr + dk * 32);

  f32x4 oacc[8] = {};
  float m = -INFINITY, li = 0.f;

  const char* kgb = (const char*)(Kc + (size_t)b * S_ * NQKV_ + g * HD_);
  const char* vgb = (const char*)(Vt + ((size_t)(b * HKV_ + g) * HD_) * (size_t)S_);
  const int nc = qt + 1;

  auto stage = [&](int buf, int kc) {
#pragma unroll
    for (int j = 0; j < 4; j++) {            // K: 16KB
      int L = (w * 4 + j) * 1024 + lane * 16;
      int row = L >> 8;
      int slot = (L >> 4) & 15;
      int col = (slot ^ (row & 7)) << 4;
      const char* src = kgb + (size_t)(kc + row) * (NQKV_ * 2) + col;
      __builtin_amdgcn_global_load_lds(
          (const __attribute__((address_space(1))) unsigned int*)src,
          (__attribute__((address_space(3))) unsigned int*)((char*)&Ks[buf][0] + (w * 4 + j) * 1024),
          16, 0, 0);
    }
#pragma unroll
    for (int j = 0; j < 4; j++) {            // V: 16KB
      int L = (w * 4 + j) * 1024 + lane * 16;
      int d = L >> 7;
      int slot = (L >> 4) & 7;
      int col = (slot ^ (d & 7)) << 4;
      const char* src = vgb + ((size_t)d * S_ + kc) * 2 + col;
      __builtin_amdgcn_global_load_lds(
          (const __attribute__((address_space(1))) unsigned int*)src,
          (__attribute__((address_space(3))) unsigned int*)((char*)&Vs[buf][0] + (w * 4 + j) * 1024),
          16, 0, 0);
    }
  };

  stage(0, 0);
  __syncthreads();

  int buf = 0;
  char* prow = (char*)&Pl[w][0] + lr * 128;

  for (int c = 0; c < nc; ++c) {
    const int kc = c * 64;
    if (c + 1 < nc) stage(buf ^ 1, kc + 64);

    const char* kb_l = (const char*)&Ks[buf][0];
    const char* vb_l = (const char*)&Vs[buf][0];

    f32x4 sa[4] = {};
#pragma unroll
    for (int nf = 0; nf < 4; nf++) {
      const int rb = (nf * 16 + lr) * 256;
#pragma unroll
      for (int dk = 0; dk < 4; dk++) {
        bf16x8 kf = *reinterpret_cast<const bf16x8*>(kb_l + rb + (((u32)(dk * 64 + lg * 16)) ^ sw));
        sa[nf] = __builtin_amdgcn_mfma_f32_16x16x32_bf16(kf, qf[dk], sa[nf], 0, 0, 0);
      }
    }

    float t[16];
    const bool full = (kc + 63 <= qlo);
#pragma unroll
    for (int nf = 0; nf < 4; nf++)
#pragma unroll
      for (int r = 0; r < 4; r++) {
        float v = sa[nf][r] * k1;
        if (!full) v = (kc + nf * 16 + lg * 4 + r <= qi) ? v : -INFINITY;
        t[nf * 4 + r] = v;
      }

    float tm = t[0];
#pragma unroll
    for (int i = 1; i < 16; i++) tm = fmaxf(tm, t[i]);
    tm = fmaxf(tm, __shfl_xor(tm, 16));
    tm = fmaxf(tm, __shfl_xor(tm, 32));

    if (!__all(tm <= m + 8.f)) {
      float mnew = fmaxf(m, tm);
      float corr = __builtin_amdgcn_exp2f(m - mnew);
      li *= corr;
#pragma unroll
      for (int r = 0; r < 4; r++) {
        float cc = __shfl(corr, (lane & 48) + lg * 4 + r);
#pragma unroll
        for (int df = 0; df < 8; df++) oacc[df][r] *= cc;
      }
      m = mnew;
    }

    float ps = 0.f;
#pragma unroll
    for (int nf = 0; nf < 4; nf++) {
      float p0 = __builtin_amdgcn_exp2f(t[nf * 4 + 0] - m);
      float p1 = __builtin_amdgcn_exp2f(t[nf * 4 + 1] - m);
      float p2 = __builtin_amdgcn_exp2f(t[nf * 4 + 2] - m);
      float p3 = __builtin_amdgcn_exp2f(t[nf * 4 + 3] - m);
      ps += (p0 + p1) + (p2 + p3);
      *(u32*)(prow + (((u32)(nf * 32 + lg * 8)) ^ sw))     = pkbf(p0, p1);
      *(u32*)(prow + (((u32)(nf * 32 + lg * 8 + 4)) ^ sw)) = pkbf(p2, p3);
    }
    ps += __shfl_xor(ps, 16);
    ps += __shfl_xor(ps, 32);
    li += ps;

    asm volatile("" ::: "memory");

#pragma unroll
    for (int kh = 0; kh < 2; kh++) {
      bf16x8 pf = *reinterpret_cast<const bf16x8*>(prow + (((u32)(kh * 64 + lg * 16)) ^ sw));
#pragma unroll
      for (int df = 0; df < 8; df++) {
        const int row = df * 16 + lr;
        bf16x8 vf = *reinterpret_cast<const bf16x8*>(vb_l + row * 128 + (((u32)(kh * 64 + lg * 16)) ^ sw));
        oacc[df] = __builtin_amdgcn_mfma_f32_16x16x32_bf16(pf, vf, oacc[df], 0, 0, 0);
      }
    }

    __syncthreads();
    buf ^= 1;
  }

#pragma unroll
  for (int r = 0; r < 4; r++) {
    float lsum = __shfl(li, (lane & 48) + lg * 4 + r);
    float inv = 1.f / lsum;
    const int qrow = qlo + lg * 4 + r;
    u16* orow = Ab + ((size_t)((b * S_ + qrow) * H_ + h)) * HD_ + lr;
#pragma unroll
    for (int df = 0; df < 8; df++)
      orow[df * 16] = f2bf(oacc[df][r] * inv);
  }
}

// ---------------- launch ----------------
extern "C" void kernel_launch(void* const* d_in, const int* in_sizes, int n_in,
                              void* d_out, int out_size, void* d_ws, size_t ws_size,
                              hipStream_t stream) {
  const float* x    = (const float*)d_in[0];
  const float* cosp = (const float*)d_in[1];
  const float* sinp = (const float*)d_in[2];
  const float* wq   = (const float*)d_in[3];
  const float* wk   = (const float*)d_in[4];
  const float* wv   = (const float*)d_in[5];
  const float* wo   = (const float*)d_in[6];
  float* out = (float*)d_out;

  char* ws = (char*)d_ws;
  size_t off = 0;
  auto alloc = [&](size_t bytes) -> void* {
    void* p = ws + off;
    off += (bytes + 255) & ~(size_t)255;
    return p;
  };
  u16* xb     = (u16*)alloc((size_t)MQ_ * DIM_ * 2);
  u16* wqkvT  = (u16*)alloc((size_t)NQKV_ * DIM_ * 2);
  u16* woT    = (u16*)alloc((size_t)DIM_ * DIM_ * 2);
  u16* Cq     = (u16*)alloc((size_t)MQ_ * NQKV_ * 2);   // fused QKV (bf16)
  u16* Vt     = (u16*)alloc((size_t)MQ_ * NKV_ * 2);
  u16* Ab     = (u16*)alloc((size_t)MQ_ * DIM_ * 2);

  const int TB = 256;
  // input cast + weight transposes (wq/wk/wv concatenated along N into wqkvT)
  cvt_x_kernel<<<(MQ_ * DIM_ / 4 + TB - 1) / TB, TB, 0, stream>>>(x, xb, MQ_ * DIM_ / 4);
  wtT_kernel<<<dim3(DIM_ / 64, DIM_ / 64), TB, 0, stream>>>(wq, wqkvT, DIM_, DIM_);
  wtT_kernel<<<dim3(NKV_ / 64, DIM_ / 64), TB, 0, stream>>>(wk, wqkvT + (size_t)KOFF_ * DIM_, DIM_, NKV_);
  wtT_kernel<<<dim3(NKV_ / 64, DIM_ / 64), TB, 0, stream>>>(wv, wqkvT + (size_t)VOFF_ * DIM_, DIM_, NKV_);
  wtT_kernel<<<dim3(DIM_ / 64, DIM_ / 64), TB, 0, stream>>>(wo, woT, DIM_, DIM_);

  // fused QKV projection (bf16 out)
  gemm128<u16><<<dim3(NQKV_ / 128, MQ_ / 128), TB, 0, stream>>>(xb, wqkvT, Cq, MQ_, NQKV_, DIM_);

  // RoPE in-place on Q and K blocks; V transpose
  rope_bf_kernel<<<(MQ_ * H_ * 64 + TB - 1) / TB, TB, 0, stream>>>(Cq, cosp, sinp, H_, MQ_ * H_ * 64);
  rope_bf_kernel<<<(MQ_ * HKV_ * 64 + TB - 1) / TB, TB, 0, stream>>>(Cq + KOFF_, cosp, sinp, HKV_, MQ_ * HKV_ * 64);
  vtT_kernel<<<dim3(S_ / 64, HD_ / 64, B_ * HKV_), TB, 0, stream>>>(Cq, Vt);

  // attention
  attn_kernel<<<dim3(S_ / 64, H_, B_), TB, 0, stream>>>(Cq, Cq + KOFF_, Vt, Ab);

  // output projection -> f32 d_out
  gemm128<float><<<dim3(DIM_ / 128, MQ_ / 128), TB, 0, stream>>>(Ab, woT, out, MQ_, DIM_, DIM_);
}

// Round 4
// 239.522 us; speedup vs baseline: 3.4738x; 1.2431x over previous
//
#include <hip/hip_runtime.h>
#include <cstdint>
#include <cmath>

#define B_ 2
#define S_ 2048
#define DIM_ 2048
#define H_ 16
#define HKV_ 4
#define HD_ 128
#define MQ_ (B_*S_)      // 4096 rows
#define NKV_ (HKV_*HD_)  // 512
#define NQKV_ 3072       // fused QKV output width
#define KOFF_ 2048       // col offset of K block in fused buffer
#define VOFF_ 2560       // col offset of V block

typedef unsigned short u16;
typedef unsigned int u32;
typedef __bf16 bf16_t;
typedef bf16_t bf16x8 __attribute__((ext_vector_type(8)));
typedef bf16_t bf16x2 __attribute__((ext_vector_type(2)));
typedef u16 u16x8 __attribute__((ext_vector_type(8)));
typedef u16 u16x4 __attribute__((ext_vector_type(4)));
typedef float f32x4 __attribute__((ext_vector_type(4)));
typedef float f32x16 __attribute__((ext_vector_type(16)));
typedef u32 u32x4 __attribute__((ext_vector_type(4)));

__device__ __forceinline__ u16 f2bf(float f) {
  union { float f; uint32_t u; } v; v.f = f;
  return (u16)((v.u + 0x7FFFu + ((v.u >> 16) & 1u)) >> 16);
}

__device__ __forceinline__ u32 pkbf(float a, float b) {
  bf16x2 v; v[0] = (bf16_t)a; v[1] = (bf16_t)b;
  return __builtin_bit_cast(u32, v);
}

__device__ __forceinline__ float bf2f(u16 u) {
  union { u32 u; float f; } v; v.u = ((u32)u) << 16;
  return v.f;
}

// ---------------- conversion kernels ----------------

__global__ void cvt_x_kernel(const float* __restrict__ in, u16* __restrict__ out, int n4) {
  int i = blockIdx.x * blockDim.x + threadIdx.x;
  if (i >= n4) return;
  float4 v = reinterpret_cast<const float4*>(in)[i];
  u16x4 o;
  o[0] = f2bf(v.x); o[1] = f2bf(v.y); o[2] = f2bf(v.z); o[3] = f2bf(v.w);
  reinterpret_cast<u16x4*>(out)[i] = o;
}

// Tiled transpose: w (f32, K x N) -> wt (bf16, N x K).
__global__ void wtT_kernel(const float* __restrict__ w, u16* __restrict__ wt, int K, int N) {
  __shared__ u16 tile[64][66];
  const int n0 = blockIdx.x * 64, k0 = blockIdx.y * 64;
  const int tx = threadIdx.x & 63, ty = threadIdx.x >> 6;
#pragma unroll
  for (int i = 0; i < 16; i++) {
    int kr = ty + i * 4;
    tile[tx][kr] = f2bf(w[(size_t)(k0 + kr) * N + n0 + tx]);
  }
  __syncthreads();
#pragma unroll
  for (int i = 0; i < 16; i++) {
    int nr = ty + i * 4;
    wt[(size_t)(n0 + nr) * K + k0 + tx] = tile[nr][tx];
  }
}

// RoPE in-place on bf16 fused-QKV buffer.
__global__ void rope_bf_kernel(u16* __restrict__ buf, const float* __restrict__ cosp,
                               const float* __restrict__ sinp, int nh, int npairs) {
  int i = blockIdx.x * blockDim.x + threadIdx.x;
  if (i >= npairs) return;
  int j = i & 63;
  int head = (i >> 6) % nh;
  int token = i / (nh * 64);
  int s = token % S_;
  u16* p = buf + (size_t)token * NQKV_ + head * HD_ + j * 2;
  u32 v = *reinterpret_cast<u32*>(p);
  float t0 = bf2f((u16)(v & 0xFFFF));
  float t1 = bf2f((u16)(v >> 16));
  float c = cosp[s * 64 + j], sn = sinp[s * 64 + j];
  u16 lo = f2bf(t0 * c - t1 * sn);
  u16 hi = f2bf(t0 * sn + t1 * c);
  *reinterpret_cast<u32*>(p) = (u32)lo | ((u32)hi << 16);
}

// Tiled transpose V: fused buf col VOFF_.. -> Vt [b][g][d][s]
__global__ void vtT_kernel(const u16* __restrict__ qkv, u16* __restrict__ vt) {
  __shared__ u16 tile[64][66];
  const int s0 = blockIdx.x * 64, d0 = blockIdx.y * 64;
  const int bg = blockIdx.z, b = bg >> 2, g = bg & 3;
  const int tx = threadIdx.x & 63, ty = threadIdx.x >> 6;
#pragma unroll
  for (int i = 0; i < 16; i++) {
    int sr = ty + i * 4;
    tile[tx][sr] = qkv[(size_t)(b * S_ + s0 + sr) * NQKV_ + VOFF_ + g * HD_ + d0 + tx];
  }
  __syncthreads();
#pragma unroll
  for (int i = 0; i < 16; i++) {
    int dr = ty + i * 4;
    vt[((size_t)bg * HD_ + d0 + dr) * S_ + s0 + tx] = tile[dr][tx];
  }
}

// ---------------- m97-structure GEMM ----------------
template <typename OutT>
__launch_bounds__(256)
__global__ void gemm128(const u16* __restrict__ A, const u16* __restrict__ Bt,
                        OutT* __restrict__ C, int M, int N, int K) {
  __shared__ u16 As[128 * 32];
  __shared__ u16 Bs[128 * 32];
  const int t = threadIdx.x;
  const int w = t >> 6, lane = t & 63;
  const int lr = lane & 15, lg = lane >> 4;
  const int m0 = blockIdx.y * 128, n0 = blockIdx.x * 128;
  const int wm = (w >> 1) * 64, wn = (w & 1) * 64;
  const int srow = lane >> 2, scol = (lane & 3) * 8;

  f32x4 acc[4][4] = {};

  for (int k0 = 0; k0 < K; k0 += 32) {
    __syncthreads();
#pragma unroll
    for (int j = 0; j < 2; j++) {
      const u16* asrc = A + (size_t)(m0 + w * 32 + j * 16 + srow) * K + k0 + scol;
      __builtin_amdgcn_global_load_lds(
          (const __attribute__((address_space(1))) unsigned int*)asrc,
          (__attribute__((address_space(3))) unsigned int*)((char*)As + w * 2048 + j * 1024 + lane * 16),
          16, 0, 0);
      const u16* bsrc = Bt + (size_t)(n0 + w * 32 + j * 16 + srow) * K + k0 + scol;
      __builtin_amdgcn_global_load_lds(
          (const __attribute__((address_space(1))) unsigned int*)bsrc,
          (__attribute__((address_space(3))) unsigned int*)((char*)Bs + w * 2048 + j * 1024 + lane * 16),
          16, 0, 0);
    }
    __syncthreads();

    bf16x8 af[4], bf[4];
#pragma unroll
    for (int i = 0; i < 4; i++)
      af[i] = *reinterpret_cast<const bf16x8*>((char*)As + (wm + i * 16 + lr) * 64 + lg * 16);
#pragma unroll
    for (int j = 0; j < 4; j++)
      bf[j] = *reinterpret_cast<const bf16x8*>((char*)Bs + (wn + j * 16 + lr) * 64 + lg * 16);
#pragma unroll
    for (int i = 0; i < 4; i++)
#pragma unroll
      for (int j = 0; j < 4; j++)
        acc[i][j] = __builtin_amdgcn_mfma_f32_16x16x32_bf16(af[i], bf[j], acc[i][j], 0, 0, 0);
  }

#pragma unroll
  for (int i = 0; i < 4; i++)
#pragma unroll
    for (int j = 0; j < 4; j++)
#pragma unroll
      for (int r = 0; r < 4; r++) {
        int row = m0 + wm + i * 16 + lg * 4 + r;
        int col = n0 + wn + j * 16 + lr;
        if constexpr (__is_same(OutT, float))
          C[(size_t)row * N + col] = acc[i][j][r];
        else
          C[(size_t)row * N + col] = f2bf(acc[i][j][r]);
      }
}

// ---------------- flash attention v3 ----------------
// Block = (q-tile of 32, GQA group g, batch b). 4 waves = 4 heads sharing K/V.
// 32x32x16 MFMA, QBLK=32/wave, KVBLK=64, P in registers (cvt_pk + shfl_xor32),
// counted-vmcnt double-buffered staging (T3/T4).
__launch_bounds__(256, 2)
__global__ void attn_kernel(const u16* __restrict__ Qc, const u16* __restrict__ Kc,
                            const u16* __restrict__ Vt, u16* __restrict__ Ab) {
  __shared__ u16 Ks[2][64 * 128];   // [key][d] 256B rows, 16-slot swizzle
  __shared__ u16 Vs[2][128 * 64];   // [d][key] 128B rows, 8-slot swizzle

  const int bk = blockIdx.x;
  const int i = bk >> 3, gb = bk & 7;
  const int g = gb & 3, b = gb >> 2;
  const int qt = (i < 32) ? (63 - i) : (i - 32);  // heavy-first, c/c+256 complementary
  const int w = threadIdx.x >> 6, lane = threadIdx.x & 63;
  const int l31 = lane & 31, hi = lane >> 5;
  const int h = g * 4 + w;                        // wave = head within group
  const int qbase = qt * 32;
  const int qi = qbase + l31;
  const float k1 = 0.08838834764831845f * 1.4426950408889634f; // scale*log2e

  // Q fragments (B-operand): Q[qbase+l31][dk*16 + hi*8 + e]
  bf16x8 qf[8];
  const u16* qptr = Qc + (size_t)(b * S_ + qi) * NQKV_ + h * HD_ + hi * 8;
#pragma unroll
  for (int dk = 0; dk < 8; dk++)
    qf[dk] = *reinterpret_cast<const bf16x8*>(qptr + dk * 16);

  f32x16 oacc[4] = {};
  float m = -INFINITY, li = 0.f;

  const char* kgb = (const char*)(Kc + (size_t)b * S_ * NQKV_ + g * HD_);
  const char* vgb = (const char*)(Vt + ((size_t)(b * HKV_ + g) * HD_) * (size_t)S_);
  const int nc = (qt >> 1) + 1;

  auto stage = [&](int buf, int kc) {
#pragma unroll
    for (int j = 0; j < 4; j++) {            // K: 16KB, wave's 4x1KB slices
      int L = (w * 4 + j) * 1024 + lane * 16;
      int key = L >> 8;
      int slot = (L >> 4) & 15;
      const char* src = kgb + (size_t)(kc + key) * (NQKV_ * 2) + ((slot ^ (key & 15)) << 4);
      __builtin_amdgcn_global_load_lds(
          (const __attribute__((address_space(1))) unsigned int*)src,
          (__attribute__((address_space(3))) unsigned int*)((char*)&Ks[buf][0] + (w * 4 + j) * 1024),
          16, 0, 0);
    }
#pragma unroll
    for (int j = 0; j < 4; j++) {            // V: 16KB
      int L = (w * 4 + j) * 1024 + lane * 16;
      int d = L >> 7;
      int slot = (L >> 4) & 7;
      const char* src = vgb + ((size_t)d * S_ + kc) * 2 + ((slot ^ (d & 7)) << 4);
      __builtin_amdgcn_global_load_lds(
          (const __attribute__((address_space(1))) unsigned int*)src,
          (__attribute__((address_space(3))) unsigned int*)((char*)&Vs[buf][0] + (w * 4 + j) * 1024),
          16, 0, 0);
    }
  };

  stage(0, 0);
  if (nc > 1) stage(1, 64);

  for (int c = 0; c < nc; ++c) {
    // counted wait: keep next chunk's 8 loads in flight (T4); drain only on last
    if (c + 1 < nc) asm volatile("s_waitcnt vmcnt(8)" ::: "memory");
    else            asm volatile("s_waitcnt vmcnt(0)" ::: "memory");
    __builtin_amdgcn_s_barrier();

    const char* kb_l = (const char*)&Ks[c & 1][0];
    const char* vb_l = (const char*)&Vs[c & 1][0];
    const int kc = c * 64;

    // QK^T swapped: sa[kb] = K-rows x Q -> D[key][q=l31]
    f32x16 sa0 = {}, sa1 = {};
#pragma unroll
    for (int dk = 0; dk < 8; dk++) {
      int key0 = l31;
      bf16x8 kf0 = *reinterpret_cast<const bf16x8*>(kb_l + key0 * 256 + (((dk * 2 + hi) ^ (key0 & 15)) << 4));
      sa0 = __builtin_amdgcn_mfma_f32_32x32x16_bf16(kf0, qf[dk], sa0, 0, 0, 0);
    }
#pragma unroll
    for (int dk = 0; dk < 8; dk++) {
      int key1 = 32 + l31;
      bf16x8 kf1 = *reinterpret_cast<const bf16x8*>(kb_l + key1 * 256 + (((dk * 2 + hi) ^ (key1 & 15)) << 4));
      sa1 = __builtin_amdgcn_mfma_f32_32x32x16_bf16(kf1, qf[dk], sa1, 0, 0, 0);
    }

    // scale + causal mask (only last chunk is partial)
    float t0[16], t1[16];
    const bool edge = (kc + 63 > qbase);
#pragma unroll
    for (int r = 0; r < 16; r++) {
      int kl = (r & 3) + 8 * (r >> 2) + 4 * hi;
      float v0 = sa0[r] * k1;
      float v1 = sa1[r] * k1;
      if (edge) {
        v0 = (kc + kl <= qi) ? v0 : -INFINITY;
        v1 = (kc + 32 + kl <= qi) ? v1 : -INFINITY;
      }
      t0[r] = v0; t1[r] = v1;
    }

    // tree max over this lane's 32 + partner's 32
    float mx[8];
#pragma unroll
    for (int r = 0; r < 8; r++)
      mx[r] = fmaxf(fmaxf(t0[r], t0[r + 8]), fmaxf(t1[r], t1[r + 8]));
    mx[0] = fmaxf(mx[0], mx[4]); mx[1] = fmaxf(mx[1], mx[5]);
    mx[2] = fmaxf(mx[2], mx[6]); mx[3] = fmaxf(mx[3], mx[7]);
    mx[0] = fmaxf(fmaxf(mx[0], mx[1]), fmaxf(mx[2], mx[3]));
    float tm = fmaxf(mx[0], __shfl_xor(mx[0], 32));

    // defer-max rescale (T13)
    if (!__all(tm <= m + 8.f)) {
      float mnew = fmaxf(m, tm);
      float corr = __builtin_amdgcn_exp2f(m - mnew);
      li *= corr;
#pragma unroll
      for (int r = 0; r < 16; r++) {
        float cc = __shfl(corr, (r & 3) + 8 * (r >> 2) + 4 * hi);
#pragma unroll
        for (int df = 0; df < 4; df++) oacc[df][r] *= cc;
      }
      m = mnew;
    }

    // P = exp2(t - m) packed to bf16 pairs, in-lane + partner exchange
    u32 own0[8], own1[8], oth0[8], oth1[8];
    float ps = 0.f;
#pragma unroll
    for (int s = 0; s < 8; s++) {
      float a0 = __builtin_amdgcn_exp2f(t0[2 * s] - m);
      float b0 = __builtin_amdgcn_exp2f(t0[2 * s + 1] - m);
      float a1 = __builtin_amdgcn_exp2f(t1[2 * s] - m);
      float b1 = __builtin_amdgcn_exp2f(t1[2 * s + 1] - m);
      ps += (a0 + b0) + (a1 + b1);
      own0[s] = pkbf(a0, b0);
      own1[s] = pkbf(a1, b1);
    }
    ps += __shfl_xor(ps, 32);
    li += ps;
#pragma unroll
    for (int s = 0; s < 8; s++) {
      oth0[s] = (u32)__shfl_xor((int)own0[s], 32);
      oth1[s] = (u32)__shfl_xor((int)own1[s], 32);
    }

    // PV: oacc[df] += P[q][k] * V^T[d][k], 4 k-slices of 16
#pragma unroll
    for (int ks = 0; ks < 4; ks++) {
      const u32* ow = (ks < 2) ? own0 : own1;
      const u32* ot = (ks < 2) ? oth0 : oth1;
      const int bo = 4 * (ks & 1);
      u32x4 pw;
      pw[0] = hi ? ot[bo + 2] : ow[bo];
      pw[1] = hi ? ot[bo + 3] : ow[bo + 1];
      pw[2] = hi ? ow[bo + 2] : ot[bo];
      pw[3] = hi ? ow[bo + 3] : ot[bo + 1];
      bf16x8 pf = __builtin_bit_cast(bf16x8, pw);
#pragma unroll
      for (int df = 0; df < 4; df++) {
        int d = df * 32 + l31;
        bf16x8 vf = *reinterpret_cast<const bf16x8*>(vb_l + d * 128 + (((ks * 2 + hi) ^ (d & 7)) << 4));
        oacc[df] = __builtin_amdgcn_mfma_f32_32x32x16_bf16(pf, vf, oacc[df], 0, 0, 0);
      }
    }

    __builtin_amdgcn_s_barrier();   // all waves done reading buf[c&1]
    if (c + 2 < nc) stage(c & 1, kc + 128);
  }

  // epilogue: normalize, write bf16 [b][s][H][128]
#pragma unroll
  for (int r = 0; r < 16; r++) {
    int qrow = (r & 3) + 8 * (r >> 2) + 4 * hi;
    float lsum = __shfl(li, qrow);
    float inv = 1.f / lsum;
    u16* orow = Ab + ((size_t)((b * S_ + qbase + qrow) * H_ + h)) * HD_ + l31;
#pragma unroll
    for (int df = 0; df < 4; df++)
      orow[df * 32] = f2bf(oacc[df][r] * inv);
  }
}

// ---------------- launch ----------------
extern "C" void kernel_launch(void* const* d_in, const int* in_sizes, int n_in,
                              void* d_out, int out_size, void* d_ws, size_t ws_size,
                              hipStream_t stream) {
  const float* x    = (const float*)d_in[0];
  const float* cosp = (const float*)d_in[1];
  const float* sinp = (const float*)d_in[2];
  const float* wq   = (const float*)d_in[3];
  const float* wk   = (const float*)d_in[4];
  const float* wv   = (const float*)d_in[5];
  const float* wo   = (const float*)d_in[6];
  float* out = (float*)d_out;

  char* ws = (char*)d_ws;
  size_t off = 0;
  auto alloc = [&](size_t bytes) -> void* {
    void* p = ws + off;
    off += (bytes + 255) & ~(size_t)255;
    return p;
  };
  u16* xb     = (u16*)alloc((size_t)MQ_ * DIM_ * 2);
  u16* wqkvT  = (u16*)alloc((size_t)NQKV_ * DIM_ * 2);
  u16* woT    = (u16*)alloc((size_t)DIM_ * DIM_ * 2);
  u16* Cq     = (u16*)alloc((size_t)MQ_ * NQKV_ * 2);   // fused QKV (bf16)
  u16* Vt     = (u16*)alloc((size_t)MQ_ * NKV_ * 2);
  u16* Ab     = (u16*)alloc((size_t)MQ_ * DIM_ * 2);

  const int TB = 256;
  cvt_x_kernel<<<(MQ_ * DIM_ / 4 + TB - 1) / TB, TB, 0, stream>>>(x, xb, MQ_ * DIM_ / 4);
  wtT_kernel<<<dim3(DIM_ / 64, DIM_ / 64), TB, 0, stream>>>(wq, wqkvT, DIM_, DIM_);
  wtT_kernel<<<dim3(NKV_ / 64, DIM_ / 64), TB, 0, stream>>>(wk, wqkvT + (size_t)KOFF_ * DIM_, DIM_, NKV_);
  wtT_kernel<<<dim3(NKV_ / 64, DIM_ / 64), TB, 0, stream>>>(wv, wqkvT + (size_t)VOFF_ * DIM_, DIM_, NKV_);
  wtT_kernel<<<dim3(DIM_ / 64, DIM_ / 64), TB, 0, stream>>>(wo, woT, DIM_, DIM_);

  // fused QKV projection (bf16 out)
  gemm128<u16><<<dim3(NQKV_ / 128, MQ_ / 128), TB, 0, stream>>>(xb, wqkvT, Cq, MQ_, NQKV_, DIM_);

  // RoPE in-place on Q and K blocks; V transpose
  rope_bf_kernel<<<(MQ_ * H_ * 64 + TB - 1) / TB, TB, 0, stream>>>(Cq, cosp, sinp, H_, MQ_ * H_ * 64);
  rope_bf_kernel<<<(MQ_ * HKV_ * 64 + TB - 1) / TB, TB, 0, stream>>>(Cq + KOFF_, cosp, sinp, HKV_, MQ_ * HKV_ * 64);
  vtT_kernel<<<dim3(S_ / 64, HD_ / 64, B_ * HKV_), TB, 0, stream>>>(Cq, Vt);

  // attention: 512 blocks = 64 q-tiles x 4 groups x 2 batch
  attn_kernel<<<dim3(64 * 8), TB, 0, stream>>>(Cq, Cq + KOFF_, Vt, Ab);

  // output projection -> f32 d_out
  gemm128<float><<<dim3(DIM_ / 128, MQ_ / 128), TB, 0, stream>>>(Ab, woT, out, MQ_, DIM_, DIM_);
}

// Round 5
// 237.735 us; speedup vs baseline: 3.4999x; 1.0075x over previous
//
#include <hip/hip_runtime.h>
#include <cstdint>
#include <cmath>

#define B_ 2
#define S_ 2048
#define DIM_ 2048
#define H_ 16
#define HKV_ 4
#define HD_ 128
#define MQ_ (B_*S_)      // 4096 rows
#define NKV_ (HKV_*HD_)  // 512
#define NQKV_ 3072       // fused QKV output width
#define KOFF_ 2048       // col offset of K block in fused buffer
#define VOFF_ 2560       // col offset of V block

typedef unsigned short u16;
typedef unsigned int u32;
typedef __bf16 bf16_t;
typedef bf16_t bf16x8 __attribute__((ext_vector_type(8)));
typedef bf16_t bf16x2 __attribute__((ext_vector_type(2)));
typedef u16 u16x8 __attribute__((ext_vector_type(8)));
typedef u16 u16x4 __attribute__((ext_vector_type(4)));
typedef float f32x4 __attribute__((ext_vector_type(4)));
typedef float f32x16 __attribute__((ext_vector_type(16)));
typedef u32 u32x4 __attribute__((ext_vector_type(4)));

__device__ __forceinline__ u16 f2bf(float f) {
  union { float f; uint32_t u; } v; v.f = f;
  return (u16)((v.u + 0x7FFFu + ((v.u >> 16) & 1u)) >> 16);
}

__device__ __forceinline__ u32 pkbf(float a, float b) {
  bf16x2 v; v[0] = (bf16_t)a; v[1] = (bf16_t)b;
  return __builtin_bit_cast(u32, v);
}

__device__ __forceinline__ float bf2f(u16 u) {
  union { u32 u; float f; } v; v.u = ((u32)u) << 16;
  return v.f;
}

// ---------------- conversion kernels ----------------

__global__ void cvt_x_kernel(const float* __restrict__ in, u16* __restrict__ out, int n4) {
  int i = blockIdx.x * blockDim.x + threadIdx.x;
  if (i >= n4) return;
  float4 v = reinterpret_cast<const float4*>(in)[i];
  u16x4 o;
  o[0] = f2bf(v.x); o[1] = f2bf(v.y); o[2] = f2bf(v.z); o[3] = f2bf(v.w);
  reinterpret_cast<u16x4*>(out)[i] = o;
}

// All four weight transposes in one launch. grid (80, 32).
// z<32: wq->wqkvT[:, n0..], z<40: wk, z<48: wv, else wo->woT. All K=2048.
__global__ void wtT_all_kernel(const float* __restrict__ wq, const float* __restrict__ wk,
                               const float* __restrict__ wv, const float* __restrict__ wo,
                               u16* __restrict__ wqkvT, u16* __restrict__ woT) {
  __shared__ u16 tile[64][66];
  const int z = blockIdx.x;
  const float* src; u16* dst; int N, n0;
  if (z < 32)      { src = wq; dst = wqkvT;                          N = 2048; n0 = z * 64; }
  else if (z < 40) { src = wk; dst = wqkvT + (size_t)KOFF_ * DIM_;   N = 512;  n0 = (z - 32) * 64; }
  else if (z < 48) { src = wv; dst = wqkvT + (size_t)VOFF_ * DIM_;   N = 512;  n0 = (z - 40) * 64; }
  else             { src = wo; dst = woT;                            N = 2048; n0 = (z - 48) * 64; }
  const int k0 = blockIdx.y * 64;
  const int tx = threadIdx.x & 63, ty = threadIdx.x >> 6;
#pragma unroll
  for (int i = 0; i < 16; i++) {
    int kr = ty + i * 4;
    tile[tx][kr] = f2bf(src[(size_t)(k0 + kr) * N + n0 + tx]);
  }
  __syncthreads();
#pragma unroll
  for (int i = 0; i < 16; i++) {
    int nr = ty + i * 4;
    dst[(size_t)(n0 + nr) * DIM_ + k0 + tx] = tile[nr][tx];
  }
}

// RoPE in-place on bf16 fused-QKV buffer; heads 0..15 = Q, 16..19 = K (cols head*128).
__global__ void rope_bf_kernel(u16* __restrict__ buf, const float* __restrict__ cosp,
                               const float* __restrict__ sinp, int npairs) {
  int i = blockIdx.x * blockDim.x + threadIdx.x;
  if (i >= npairs) return;
  int j = i & 63;
  int head = (i >> 6) % 20;
  int token = i / (20 * 64);
  int s = token % S_;
  u16* p = buf + (size_t)token * NQKV_ + head * HD_ + j * 2;
  u32 v = *reinterpret_cast<u32*>(p);
  float t0 = bf2f((u16)(v & 0xFFFF));
  float t1 = bf2f((u16)(v >> 16));
  float c = cosp[s * 64 + j], sn = sinp[s * 64 + j];
  u16 lo = f2bf(t0 * c - t1 * sn);
  u16 hi = f2bf(t0 * sn + t1 * c);
  *reinterpret_cast<u32*>(p) = (u32)lo | ((u32)hi << 16);
}

// Tiled transpose V: fused buf col VOFF_.. -> Vt [b][g][d][s]
__global__ void vtT_kernel(const u16* __restrict__ qkv, u16* __restrict__ vt) {
  __shared__ u16 tile[64][66];
  const int s0 = blockIdx.x * 64, d0 = blockIdx.y * 64;
  const int bg = blockIdx.z, b = bg >> 2, g = bg & 3;
  const int tx = threadIdx.x & 63, ty = threadIdx.x >> 6;
#pragma unroll
  for (int i = 0; i < 16; i++) {
    int sr = ty + i * 4;
    tile[tx][sr] = qkv[(size_t)(b * S_ + s0 + sr) * NQKV_ + VOFF_ + g * HD_ + d0 + tx];
  }
  __syncthreads();
#pragma unroll
  for (int i = 0; i < 16; i++) {
    int dr = ty + i * 4;
    vt[((size_t)bg * HD_ + d0 + dr) * S_ + s0 + tx] = tile[dr][tx];
  }
}

// ---------------- m97-structure GEMM ----------------
template <typename OutT>
__launch_bounds__(256)
__global__ void gemm128(const u16* __restrict__ A, const u16* __restrict__ Bt,
                        OutT* __restrict__ C, int M, int N, int K) {
  __shared__ u16 As[128 * 32];
  __shared__ u16 Bs[128 * 32];
  const int t = threadIdx.x;
  const int w = t >> 6, lane = t & 63;
  const int lr = lane & 15, lg = lane >> 4;
  const int m0 = blockIdx.y * 128, n0 = blockIdx.x * 128;
  const int wm = (w >> 1) * 64, wn = (w & 1) * 64;
  const int srow = lane >> 2, scol = (lane & 3) * 8;

  f32x4 acc[4][4] = {};

  for (int k0 = 0; k0 < K; k0 += 32) {
    __syncthreads();
#pragma unroll
    for (int j = 0; j < 2; j++) {
      const u16* asrc = A + (size_t)(m0 + w * 32 + j * 16 + srow) * K + k0 + scol;
      __builtin_amdgcn_global_load_lds(
          (const __attribute__((address_space(1))) unsigned int*)asrc,
          (__attribute__((address_space(3))) unsigned int*)((char*)As + w * 2048 + j * 1024 + lane * 16),
          16, 0, 0);
      const u16* bsrc = Bt + (size_t)(n0 + w * 32 + j * 16 + srow) * K + k0 + scol;
      __builtin_amdgcn_global_load_lds(
          (const __attribute__((address_space(1))) unsigned int*)bsrc,
          (__attribute__((address_space(3))) unsigned int*)((char*)Bs + w * 2048 + j * 1024 + lane * 16),
          16, 0, 0);
    }
    __syncthreads();

    bf16x8 af[4], bf[4];
#pragma unroll
    for (int i = 0; i < 4; i++)
      af[i] = *reinterpret_cast<const bf16x8*>((char*)As + (wm + i * 16 + lr) * 64 + lg * 16);
#pragma unroll
    for (int j = 0; j < 4; j++)
      bf[j] = *reinterpret_cast<const bf16x8*>((char*)Bs + (wn + j * 16 + lr) * 64 + lg * 16);
#pragma unroll
    for (int i = 0; i < 4; i++)
#pragma unroll
      for (int j = 0; j < 4; j++)
        acc[i][j] = __builtin_amdgcn_mfma_f32_16x16x32_bf16(af[i], bf[j], acc[i][j], 0, 0, 0);
  }

#pragma unroll
  for (int i = 0; i < 4; i++)
#pragma unroll
    for (int j = 0; j < 4; j++)
#pragma unroll
      for (int r = 0; r < 4; r++) {
        int row = m0 + wm + i * 16 + lg * 4 + r;
        int col = n0 + wn + j * 16 + lr;
        if constexpr (__is_same(OutT, float))
          C[(size_t)row * N + col] = acc[i][j][r];
        else
          C[(size_t)row * N + col] = f2bf(acc[i][j][r]);
      }
}

// ---------------- flash attention v4: software-pipelined ----------------
// Block = (q-tile of 32, group g, batch b); 4 waves = 4 heads sharing K/V.
// Iter c: issue QK(c+1) MFMAs first, softmax(c) VALU under MFMA latency, then PV(c).
// Counted vmcnt: prologue 12, steady 4, drain 0 on last chunk.
__launch_bounds__(256, 2)
__global__ void attn_kernel(const u16* __restrict__ Qc, const u16* __restrict__ Kc,
                            const u16* __restrict__ Vt, u16* __restrict__ Ab) {
  __shared__ u16 Ks[2][64 * 128];   // [key][d] 256B rows, 16-slot swizzle
  __shared__ u16 Vs[2][128 * 64];   // [d][key] 128B rows, 8-slot swizzle

  const int bk = blockIdx.x;
  const int i = bk >> 3, gb = bk & 7;
  const int g = gb & 3, b = gb >> 2;
  const int qt = (i < 32) ? (63 - i) : (i - 32);  // heavy-first, complementary pairs
  const int w = threadIdx.x >> 6, lane = threadIdx.x & 63;
  const int l31 = lane & 31, hi = lane >> 5;
  const int h = g * 4 + w;                        // wave = head within group
  const int qbase = qt * 32;
  const int qi = qbase + l31;
  const float k1 = 0.08838834764831845f * 1.4426950408889634f; // scale*log2e

  bf16x8 qf[8];
  const u16* qptr = Qc + (size_t)(b * S_ + qi) * NQKV_ + h * HD_ + hi * 8;
#pragma unroll
  for (int dk = 0; dk < 8; dk++)
    qf[dk] = *reinterpret_cast<const bf16x8*>(qptr + dk * 16);

  f32x16 oacc[4] = {};
  float m = -INFINITY, li = 0.f;

  const char* kgb = (const char*)(Kc + (size_t)b * S_ * NQKV_ + g * HD_);
  const char* vgb = (const char*)(Vt + ((size_t)(b * HKV_ + g) * HD_) * (size_t)S_);
  const int nc = (qt >> 1) + 1;

  auto stage = [&](int buf, int kc) {
#pragma unroll
    for (int j = 0; j < 4; j++) {            // K: 16KB, wave's 4x1KB slices
      int L = (w * 4 + j) * 1024 + lane * 16;
      int key = L >> 8;
      int slot = (L >> 4) & 15;
      const char* src = kgb + (size_t)(kc + key) * (NQKV_ * 2) + ((slot ^ (key & 15)) << 4);
      __builtin_amdgcn_global_load_lds(
          (const __attribute__((address_space(1))) unsigned int*)src,
          (__attribute__((address_space(3))) unsigned int*)((char*)&Ks[buf][0] + (w * 4 + j) * 1024),
          16, 0, 0);
    }
#pragma unroll
    for (int j = 0; j < 4; j++) {            // V: 16KB
      int L = (w * 4 + j) * 1024 + lane * 16;
      int d = L >> 7;
      int slot = (L >> 4) & 7;
      const char* src = vgb + ((size_t)d * S_ + kc) * 2 + ((slot ^ (d & 7)) << 4);
      __builtin_amdgcn_global_load_lds(
          (const __attribute__((address_space(1))) unsigned int*)src,
          (__attribute__((address_space(3))) unsigned int*)((char*)&Vs[buf][0] + (w * 4 + j) * 1024),
          16, 0, 0);
    }
  };

  auto qk = [&](int buf, f32x16& s0, f32x16& s1) {
    const char* kb_l = (const char*)&Ks[buf][0];
    __builtin_amdgcn_s_setprio(1);
#pragma unroll
    for (int dk = 0; dk < 8; dk++) {
      bf16x8 kf = *reinterpret_cast<const bf16x8*>(kb_l + l31 * 256 + (((dk * 2 + hi) ^ (l31 & 15)) << 4));
      s0 = __builtin_amdgcn_mfma_f32_32x32x16_bf16(kf, qf[dk], s0, 0, 0, 0);
    }
#pragma unroll
    for (int dk = 0; dk < 8; dk++) {
      int key = 32 + l31;
      bf16x8 kf = *reinterpret_cast<const bf16x8*>(kb_l + key * 256 + (((dk * 2 + hi) ^ (key & 15)) << 4));
      s1 = __builtin_amdgcn_mfma_f32_32x32x16_bf16(kf, qf[dk], s1, 0, 0, 0);
    }
    __builtin_amdgcn_s_setprio(0);
  };

  // prologue: stage chunks 0,1; wait until K(0) landed; QK(0)
  stage(0, 0);
  if (nc > 1) {
    stage(1, 64);
    asm volatile("s_waitcnt vmcnt(12)" ::: "memory");
  } else {
    asm volatile("s_waitcnt vmcnt(4)" ::: "memory");
  }
  __builtin_amdgcn_s_barrier();

  f32x16 sc0 = {}, sc1 = {};
  qk(0, sc0, sc1);

  for (int c = 0; c < nc; ++c) {
    const int kc = c * 64;
    const bool have_next = (c + 1 < nc);
    f32x16 sn0 = {}, sn1 = {};

    if (have_next) {
      // V(c) and K(c+1) landed; V(c+1) (+ any staged c+2) still in flight
      asm volatile("s_waitcnt vmcnt(4)" ::: "memory");
      __builtin_amdgcn_s_barrier();
      qk((c + 1) & 1, sn0, sn1);
    } else {
      asm volatile("s_waitcnt vmcnt(0)" ::: "memory");
      __builtin_amdgcn_s_barrier();
    }

    // ---- softmax(c) on sc0/sc1 (keys kc..kc+63), overlaps QK(c+1) latency ----
    const bool edge = (kc + 63 > qbase);
#pragma unroll
    for (int r = 0; r < 16; r++) {
      int kl = (r & 3) + 8 * (r >> 2) + 4 * hi;
      float v0 = sc0[r] * k1;
      float v1 = sc1[r] * k1;
      if (edge) {
        v0 = (kc + kl <= qi) ? v0 : -INFINITY;
        v1 = (kc + 32 + kl <= qi) ? v1 : -INFINITY;
      }
      sc0[r] = v0; sc1[r] = v1;
    }

    float mx[8];
#pragma unroll
    for (int r = 0; r < 8; r++)
      mx[r] = fmaxf(fmaxf(sc0[r], sc0[r + 8]), fmaxf(sc1[r], sc1[r + 8]));
    mx[0] = fmaxf(mx[0], mx[4]); mx[1] = fmaxf(mx[1], mx[5]);
    mx[2] = fmaxf(mx[2], mx[6]); mx[3] = fmaxf(mx[3], mx[7]);
    mx[0] = fmaxf(fmaxf(mx[0], mx[1]), fmaxf(mx[2], mx[3]));
    float tm = fmaxf(mx[0], __shfl_xor(mx[0], 32));

    if (!__all(tm <= m + 8.f)) {               // defer-max (T13)
      float mnew = fmaxf(m, tm);
      float corr = __builtin_amdgcn_exp2f(m - mnew);
      li *= corr;
#pragma unroll
      for (int r = 0; r < 16; r++) {
        float cc = __shfl(corr, (r & 3) + 8 * (r >> 2) + 4 * hi);
#pragma unroll
        for (int df = 0; df < 4; df++) oacc[df][r] *= cc;
      }
      m = mnew;
    }

    u32 own0[8], own1[8], oth0[8], oth1[8];
    float ps = 0.f;
#pragma unroll
    for (int s = 0; s < 8; s++) {
      float a0 = __builtin_amdgcn_exp2f(sc0[2 * s] - m);
      float b0 = __builtin_amdgcn_exp2f(sc0[2 * s + 1] - m);
      float a1 = __builtin_amdgcn_exp2f(sc1[2 * s] - m);
      float b1 = __builtin_amdgcn_exp2f(sc1[2 * s + 1] - m);
      ps += (a0 + b0) + (a1 + b1);
      own0[s] = pkbf(a0, b0);
      own1[s] = pkbf(a1, b1);
    }
    ps += __shfl_xor(ps, 32);
    li += ps;
#pragma unroll
    for (int s = 0; s < 8; s++) {
      oth0[s] = (u32)__shfl_xor((int)own0[s], 32);
      oth1[s] = (u32)__shfl_xor((int)own1[s], 32);
    }

    // ---- PV(c) ----
    {
      const char* vb_l = (const char*)&Vs[c & 1][0];
      __builtin_amdgcn_s_setprio(1);
#pragma unroll
      for (int ks = 0; ks < 4; ks++) {
        const u32* ow = (ks < 2) ? own0 : own1;
        const u32* ot = (ks < 2) ? oth0 : oth1;
        const int bo = 4 * (ks & 1);
        u32x4 pw;
        pw[0] = hi ? ot[bo + 2] : ow[bo];
        pw[1] = hi ? ot[bo + 3] : ow[bo + 1];
        pw[2] = hi ? ow[bo + 2] : ot[bo];
        pw[3] = hi ? ow[bo + 3] : ot[bo + 1];
        bf16x8 pf = __builtin_bit_cast(bf16x8, pw);
#pragma unroll
        for (int df = 0; df < 4; df++) {
          int d = df * 32 + l31;
          bf16x8 vf = *reinterpret_cast<const bf16x8*>(vb_l + d * 128 + (((ks * 2 + hi) ^ (d & 7)) << 4));
          oacc[df] = __builtin_amdgcn_mfma_f32_32x32x16_bf16(pf, vf, oacc[df], 0, 0, 0);
        }
      }
      __builtin_amdgcn_s_setprio(0);
    }

    __builtin_amdgcn_s_barrier();           // all waves done with Ks[(c+1)&1]? (read above) & Vs[c&1]
    if (c + 2 < nc) stage(c & 1, kc + 128); // overwrite buffers just released
    if (have_next) { sc0 = sn0; sc1 = sn1; }
  }

  // epilogue: normalize, write bf16 [b][s][H][128]
#pragma unroll
  for (int r = 0; r < 16; r++) {
    int qrow = (r & 3) + 8 * (r >> 2) + 4 * hi;
    float lsum = __shfl(li, qrow);
    float inv = 1.f / lsum;
    u16* orow = Ab + ((size_t)((b * S_ + qbase + qrow) * H_ + h)) * HD_ + l31;
#pragma unroll
    for (int df = 0; df < 4; df++)
      orow[df * 32] = f2bf(oacc[df][r] * inv);
  }
}

// ---------------- launch ----------------
extern "C" void kernel_launch(void* const* d_in, const int* in_sizes, int n_in,
                              void* d_out, int out_size, void* d_ws, size_t ws_size,
                              hipStream_t stream) {
  const float* x    = (const float*)d_in[0];
  const float* cosp = (const float*)d_in[1];
  const float* sinp = (const float*)d_in[2];
  const float* wq   = (const float*)d_in[3];
  const float* wk   = (const float*)d_in[4];
  const float* wv   = (const float*)d_in[5];
  const float* wo   = (const float*)d_in[6];
  float* out = (float*)d_out;

  char* ws = (char*)d_ws;
  size_t off = 0;
  auto alloc = [&](size_t bytes) -> void* {
    void* p = ws + off;
    off += (bytes + 255) & ~(size_t)255;
    return p;
  };
  u16* xb     = (u16*)alloc((size_t)MQ_ * DIM_ * 2);
  u16* wqkvT  = (u16*)alloc((size_t)NQKV_ * DIM_ * 2);
  u16* woT    = (u16*)alloc((size_t)DIM_ * DIM_ * 2);
  u16* Cq     = (u16*)alloc((size_t)MQ_ * NQKV_ * 2);   // fused QKV (bf16)
  u16* Vt     = (u16*)alloc((size_t)MQ_ * NKV_ * 2);
  u16* Ab     = (u16*)alloc((size_t)MQ_ * DIM_ * 2);

  const int TB = 256;
  cvt_x_kernel<<<(MQ_ * DIM_ / 4 + TB - 1) / TB, TB, 0, stream>>>(x, xb, MQ_ * DIM_ / 4);
  wtT_all_kernel<<<dim3(80, 32), TB, 0, stream>>>(wq, wk, wv, wo, wqkvT, woT);

  // fused QKV projection (bf16 out)
  gemm128<u16><<<dim3(NQKV_ / 128, MQ_ / 128), TB, 0, stream>>>(xb, wqkvT, Cq, MQ_, NQKV_, DIM_);

  // RoPE in-place on Q+K blocks (heads 0..19); V transpose
  rope_bf_kernel<<<(MQ_ * 20 * 64 + TB - 1) / TB, TB, 0, stream>>>(Cq, cosp, sinp, MQ_ * 20 * 64);
  vtT_kernel<<<dim3(S_ / 64, HD_ / 64, B_ * HKV_), TB, 0, stream>>>(Cq, Vt);

  // attention: 512 blocks = 64 q-tiles x 4 groups x 2 batch
  attn_kernel<<<dim3(64 * 8), TB, 0, stream>>>(Cq, Cq + KOFF_, Vt, Ab);

  // output projection -> f32 d_out
  gemm128<float><<<dim3(DIM_ / 128, MQ_ / 128), TB, 0, stream>>>(Ab, woT, out, MQ_, DIM_, DIM_);
}